// Round 4
// baseline (2651.444 us; speedup 1.0000x reference)
//
#include <hip/hip_runtime.h>

// FlowNetC correlation: B=8, C=256, H=96, W=128, PAD=20, S2=2, GW=21, NOUT=441
// out[b, dyi*21+j, y, x] = (1/256) * sum_c in1[b,c,y,x] * in2[b,c, y+2*dyi-20, x+2*j-20]
// Double-buffered LDS: staging(buf^1) overlaps compute(buf); 1 barrier/iter, no WAR hazard.

#define BDIM 128
#define CK 8

constexpr int Bn = 8, Cn = 256, Hn = 96, Wn = 128;
constexpr int GW = 21;            // displacement grid width
constexpr int NG = 6;             // dy groups of 4 -> 24 slots (21 valid)
constexpr int U  = 168;           // staged u-span per in2 row: u = -20..147
constexpr int UP = 84;            // per-parity width of staged in2 row
constexpr int NITER = Cn / CK;    // 32
constexpr int NWG = Bn * Hn * NG; // 4608 blocks, divisible by 8 (XCDs)

// s2 staging: 4*CK*U = 5376 elements / 128 threads = 42 slots per thread per iteration
#define NSLOT 42

__global__ __launch_bounds__(BDIM) void corr_kernel(
    const float* __restrict__ in1, const float* __restrict__ in2,
    float* __restrict__ out)
{
    // parity-split staging, double-buffered
    __shared__ __align__(16) float s1[2][CK][2][Wn / 2];
    __shared__ __align__(16) float s2[2][4][CK][2][UP];

    // bijective XCD-chunked swizzle
    int orig = blockIdx.x;
    int wg = (orig & 7) * (NWG / 8) + (orig >> 3);

    int g  = wg % NG;
    int by = wg / NG;
    int y  = by % Hn;
    int b  = by / Hn;

    int tid    = threadIdx.x;
    int dl     = tid >> 5;          // 0..3 : which dy in this group
    int dyi    = g * 4 + dl;        // 0..23 (valid if < 21)
    int lane32 = tid & 31;
    int parity = lane32 >> 4;       // 0: even x, 1: odd x
    int q      = lane32 & 15;       // owns x = 8q + parity + {0,2,4,6}

    const size_t chw = (size_t)Hn * Wn;
    const float* p1 = in1 + ((size_t)b * Cn) * chw + (size_t)y * Wn;
    const float* p2 = in2 + ((size_t)b * Cn) * chw;

    // ---- precompute s2 staging slots (c0-independent) ----
    // slot s handles linear element idx = tid + s*BDIM over [4][CK][U]
    int  s2_loff[NSLOT];   // float offset within one s2 buffer
    int  s2_goff[NSLOT];   // float offset into p2 (+ c0*chw per iter); -1 if zero-fill
    {
        int y2d[4]; int rowv[4];
#pragma unroll
        for (int d = 0; d < 4; ++d) {
            int dyi2 = g * 4 + d;
            int y2   = y + dyi2 * 2 - 20;
            rowv[d]  = (dyi2 < GW) && (y2 >= 0) && (y2 < Hn);
            y2d[d]   = y2;
        }
        for (int s = 0; s < NSLOT; ++s) {
            int idx = tid + s * BDIM;      // 0..5375
            int d   = idx / (CK * U);
            int r   = idx - d * (CK * U);
            int ch  = r / U;
            int uu  = r - ch * U;          // 0..167
            int u   = uu - 20;
            // float-offset into s2[buf]: [d][ch][uu&1][uu>>1]
            s2_loff[s] = ((d * CK + ch) * 2 + (uu & 1)) * UP + (uu >> 1);
            if (rowv[d] && u >= 0 && u < Wn)
                s2_goff[s] = (int)(ch * (int)chw + y2d[d] * Wn + u);
            else
                s2_goff[s] = -1;
        }
    }
    // s1 slot k: ch=k, xg=tid (since BDIM==Wn): write s1[buf][k][tid&1][tid>>1]
    const int s1_loff = (tid & 1) * (Wn / 2) + (tid >> 1);

    float acc[GW][4];
#pragma unroll
    for (int j = 0; j < GW; ++j)
#pragma unroll
        for (int i = 0; i < 4; ++i) acc[j][i] = 0.0f;

    float* s1base = &s1[0][0][0][0];
    float* s2base = &s2[0][0][0][0][0];
    constexpr int S1SZ = CK * 2 * (Wn / 2);   // floats per s1 buffer
    constexpr int S2SZ = 4 * CK * 2 * UP;     // floats per s2 buffer

    // ---- staging helper ----
    auto stage = [&](int buf, int c0) {
        float* d1 = s1base + buf * S1SZ;
        float* d2 = s2base + buf * S2SZ;
        size_t cadv = (size_t)c0 * chw;
#pragma unroll
        for (int k = 0; k < CK; ++k)
            d1[k * 2 * (Wn / 2) + s1_loff] = p1[cadv + (size_t)k * chw + tid];
#pragma unroll
        for (int s = 0; s < NSLOT; ++s) {
            int go = s2_goff[s];
            float v = (go >= 0) ? p2[cadv + go] : 0.0f;
            d2[s2_loff[s]] = v;
        }
    };

    // ---- main loop: double-buffered ----
    stage(0, 0);
    for (int it = 0; it < NITER; ++it) {
        __syncthreads();                       // staging of buf cur visible to all
        int cur = it & 1;
        if (it + 1 < NITER) stage(cur ^ 1, (it + 1) * CK);

        const float* r1 = s1base + cur * S1SZ + parity * (Wn / 2) + 4 * q;
        const float* r2 = s2base + cur * S2SZ + (dl * CK * 2 + parity) * UP + 4 * q;
#pragma unroll
        for (int ch = 0; ch < CK; ++ch) {
            float4 a1v = *reinterpret_cast<const float4*>(r1 + ch * 2 * (Wn / 2));
            float a1[4] = {a1v.x, a1v.y, a1v.z, a1v.w};
            float b2[24];
#pragma unroll
            for (int kk = 0; kk < 6; ++kk) {
                float4 t = *reinterpret_cast<const float4*>(r2 + ch * 2 * UP + 4 * kk);
                b2[4 * kk + 0] = t.x; b2[4 * kk + 1] = t.y;
                b2[4 * kk + 2] = t.z; b2[4 * kk + 3] = t.w;
            }
#pragma unroll
            for (int j = 0; j < GW; ++j)
#pragma unroll
                for (int i = 0; i < 4; ++i)
                    acc[j][i] = fmaf(a1[i], b2[i + j], acc[j][i]);
        }
    }

    // ---- epilogue ----
    if (dyi < GW) {
        const float scale = 1.0f / 256.0f;
        int xb = 8 * q + parity;
#pragma unroll
        for (int j = 0; j < GW; ++j) {
            size_t o = (size_t)(b * (GW * GW) + dyi * GW + j);
            float* po = out + (o * Hn + y) * Wn + xb;
#pragma unroll
            for (int i = 0; i < 4; ++i)
                po[2 * i] = acc[j][i] * scale;
        }
    }
}

extern "C" void kernel_launch(void* const* d_in, const int* in_sizes, int n_in,
                              void* d_out, int out_size, void* d_ws, size_t ws_size,
                              hipStream_t stream) {
    const float* in1 = (const float*)d_in[0];
    const float* in2 = (const float*)d_in[1];
    float* out = (float*)d_out;
    corr_kernel<<<NWG, BDIM, 0, stream>>>(in1, in2, out);
}

// Round 5
// 750.825 us; speedup vs baseline: 3.5314x; 3.5314x over previous
//
#include <hip/hip_runtime.h>

// FlowNetC correlation: B=8, C=256, H=96, W=128, PAD=20, S2=2, GW=21, NOUT=441
// out[b, dyi*21+j, y, x] = (1/256) * sum_c in1[b,c,y,x] * in2[b,c, y+2*dyi-20, x+2*j-20]
// Double-buffered LDS + T14 async staging split:
//   writeout(cur from regs) -> barrier -> issue float4 loads(next)->regs -> 672 fmac (hides latency)

#define BDIM 128
#define CK 8

constexpr int Bn = 8, Cn = 256, Hn = 96, Wn = 128;
constexpr int GW = 21;            // displacement grid width
constexpr int NG = 6;             // dy groups of 4 -> 24 slots (21 valid)
constexpr int UP = 84;            // per-parity width of staged in2 row (u span 168)
constexpr int NITER = Cn / CK;    // 32
constexpr int NWG = Bn * Hn * NG; // 4608 blocks, divisible by 8 (XCDs)

#define NS2 11   // ceil(4*CK*42 vec4-slots / 128 thr) = ceil(1344/128)
#define NS1 2    // CK*32 vec4-slots / 128 thr

__global__ __launch_bounds__(BDIM) void corr_kernel(
    const float* __restrict__ in1, const float* __restrict__ in2,
    float* __restrict__ out)
{
    // parity-split staging, double-buffered
    __shared__ __align__(16) float s1[2][CK][2][Wn / 2];
    __shared__ __align__(16) float s2[2][4][CK][2][UP];

    // bijective XCD-chunked swizzle
    int orig = blockIdx.x;
    int wg = (orig & 7) * (NWG / 8) + (orig >> 3);

    int g  = wg % NG;
    int by = wg / NG;
    int y  = by % Hn;
    int b  = by / Hn;

    int tid    = threadIdx.x;
    int dl     = tid >> 5;          // 0..3 : which dy in this group
    int dyi    = g * 4 + dl;        // 0..23 (valid if < 21)
    int lane32 = tid & 31;
    int parity = lane32 >> 4;       // 0: even x, 1: odd x
    int q      = lane32 & 15;       // owns x = 8q + parity + {0,2,4,6}

    const size_t chw = (size_t)Hn * Wn;
    const float* p1 = in1 + ((size_t)b * Cn) * chw + (size_t)y * Wn;
    const float* p2 = in2 + ((size_t)b * Cn) * chw;

    // ---- precompute vectorized staging slots (c0-independent) ----
    // s2: vec4 slot idx over [4 dy][CK ch][42 vec], u = 4k-20; 20%4==0 and 128%4==0
    //     => every vec4 is fully in-bounds (5<=k<=36) or fully zero. No partials.
    int v2_goff[NS2], v2_loff[NS2];
    {
        int y2d[4], rowv[4];
#pragma unroll
        for (int d = 0; d < 4; ++d) {
            int dyi2 = g * 4 + d;
            int y2   = y + dyi2 * 2 - 20;
            rowv[d]  = (dyi2 < GW) && (y2 >= 0) && (y2 < Hn);
            y2d[d]   = y2;
        }
#pragma unroll
        for (int s = 0; s < NS2; ++s) {
            int idx = tid + s * BDIM;            // 0..1407, valid < 1344
            if (idx < 4 * CK * 42) {
                int d  = idx / (CK * 42);
                int r  = idx - d * (CK * 42);
                int ch = r / 42;
                int k  = r - ch * 42;            // vec index; u = 4k - 20
                // parity0 float2 at loff, parity1 at loff+UP
                v2_loff[s] = ((d * CK + ch) * 2) * UP + 2 * k;
                v2_goff[s] = (rowv[d] && k >= 5 && k <= 36)
                           ? (ch * (int)chw + y2d[d] * Wn + 4 * k - 20) : -1;
            } else { v2_loff[s] = -1; v2_goff[s] = -1; }
        }
    }
    // s1: vec4 slot idx over [CK ch][32 vec]
    int v1_goff[NS1], v1_loff[NS1];
#pragma unroll
    for (int s = 0; s < NS1; ++s) {
        int idx = tid + s * BDIM;                // 0..255
        int ch  = idx >> 5;
        int k   = idx & 31;
        v1_goff[s] = ch * (int)chw + 4 * k;
        v1_loff[s] = (ch * 2) * (Wn / 2) + 2 * k;
    }

    float acc[GW][4];
#pragma unroll
    for (int j = 0; j < GW; ++j)
#pragma unroll
        for (int i = 0; i < 4; ++i) acc[j][i] = 0.0f;

    float* s1base = &s1[0][0][0][0];
    float* s2base = &s2[0][0][0][0][0];
    constexpr int S1SZ = CK * 2 * (Wn / 2);   // floats per s1 buffer
    constexpr int S2SZ = 4 * CK * 2 * UP;     // floats per s2 buffer

    float4 pf1[NS1], pf2[NS2];

    // issue global loads into registers (no LDS writes -> no vmcnt on critical path)
    auto prefetch = [&](int c0) {
        size_t cadv = (size_t)c0 * chw;
#pragma unroll
        for (int s = 0; s < NS1; ++s)
            pf1[s] = *reinterpret_cast<const float4*>(p1 + cadv + v1_goff[s]);
#pragma unroll
        for (int s = 0; s < NS2; ++s) {
            float4 v{0.0f, 0.0f, 0.0f, 0.0f};
            if (v2_goff[s] >= 0)
                v = *reinterpret_cast<const float4*>(p2 + cadv + v2_goff[s]);
            pf2[s] = v;
        }
    };
    // parity-split LDS writes from the prefetch registers
    auto writeout = [&](int buf) {
        float* d1 = s1base + buf * S1SZ;
        float* d2 = s2base + buf * S2SZ;
#pragma unroll
        for (int s = 0; s < NS1; ++s) {
            float2 e{pf1[s].x, pf1[s].z};
            float2 o{pf1[s].y, pf1[s].w};
            *reinterpret_cast<float2*>(d1 + v1_loff[s]) = e;
            *reinterpret_cast<float2*>(d1 + v1_loff[s] + (Wn / 2)) = o;
        }
#pragma unroll
        for (int s = 0; s < NS2; ++s) {
            if (v2_loff[s] >= 0) {
                float2 e{pf2[s].x, pf2[s].z};
                float2 o{pf2[s].y, pf2[s].w};
                *reinterpret_cast<float2*>(d2 + v2_loff[s]) = e;
                *reinterpret_cast<float2*>(d2 + v2_loff[s] + UP) = o;
            }
        }
    };

    // ---- main loop ----
    prefetch(0);
    for (int it = 0; it < NITER; ++it) {
        int cur = it & 1;
        writeout(cur);                  // LDS writes of tile `it` (regs loaded last iter)
        __syncthreads();                // tile `it` visible; all reads of buf cur drained
        if (it + 1 < NITER) prefetch((it + 1) * CK);   // loads in flight under compute

        const float* r1 = s1base + cur * S1SZ + parity * (Wn / 2) + 4 * q;
        const float* r2 = s2base + cur * S2SZ + (dl * CK * 2 + parity) * UP + 4 * q;
#pragma unroll
        for (int ch = 0; ch < CK; ++ch) {
            float4 a1v = *reinterpret_cast<const float4*>(r1 + ch * 2 * (Wn / 2));
            float a1[4] = {a1v.x, a1v.y, a1v.z, a1v.w};
            float b2[24];
#pragma unroll
            for (int kk = 0; kk < 6; ++kk) {
                float4 t = *reinterpret_cast<const float4*>(r2 + ch * 2 * UP + 4 * kk);
                b2[4 * kk + 0] = t.x; b2[4 * kk + 1] = t.y;
                b2[4 * kk + 2] = t.z; b2[4 * kk + 3] = t.w;
            }
#pragma unroll
            for (int j = 0; j < GW; ++j)
#pragma unroll
                for (int i = 0; i < 4; ++i)
                    acc[j][i] = fmaf(a1[i], b2[i + j], acc[j][i]);
        }
    }

    // ---- epilogue (WRITE_SIZE measured exactly minimal with this pattern) ----
    if (dyi < GW) {
        const float scale = 1.0f / 256.0f;
        int xb = 8 * q + parity;
#pragma unroll
        for (int j = 0; j < GW; ++j) {
            size_t o = (size_t)(b * (GW * GW) + dyi * GW + j);
            float* po = out + (o * Hn + y) * Wn + xb;
#pragma unroll
            for (int i = 0; i < 4; ++i)
                po[2 * i] = acc[j][i] * scale;
        }
    }
}

extern "C" void kernel_launch(void* const* d_in, const int* in_sizes, int n_in,
                              void* d_out, int out_size, void* d_ws, size_t ws_size,
                              hipStream_t stream) {
    const float* in1 = (const float*)d_in[0];
    const float* in2 = (const float*)d_in[1];
    float* out = (float*)d_out;
    corr_kernel<<<NWG, BDIM, 0, stream>>>(in1, in2, out);
}